// Round 9
// baseline (509.515 us; speedup 1.0000x reference)
//
#include <hip/hip_runtime.h>
#include <math.h>

// Problem constants: H=300, D=600, B=256 graphs, Nu=Nv=8192, batch SORTED.
#define HDIM 300
#define DDIM 600
#define NGR  256

typedef float vf4 __attribute__((ext_vector_type(4)));
typedef float vf2 __attribute__((ext_vector_type(2)));

__device__ __forceinline__ float wred_sum(float v){
  #pragma unroll
  for(int o=32;o;o>>=1) v += __shfl_xor(v,o,64);
  return v;
}
__device__ __forceinline__ float wred_max(float v){
  #pragma unroll
  for(int o=32;o;o>>=1) v = fmaxf(v,__shfl_xor(v,o,64));
  return v;
}
__device__ __forceinline__ float sigm(float x){ return 1.f/(1.f+expf(-x)); }

// sum across the 4 16-lane groups (xor bit4 then bit5), all lanes -> total
__device__ __forceinline__ float xgrp_sum(float v){
  v += __shfl_xor(v,16,64);
  v += __shfl_xor(v,32,64);
  return v;
}
__device__ __forceinline__ void xgrp_sum4(vf4& v){
  v.x += __shfl_xor(v.x,16,64); v.y += __shfl_xor(v.y,16,64);
  v.z += __shfl_xor(v.z,16,64); v.w += __shfl_xor(v.w,16,64);
  v.x += __shfl_xor(v.x,32,64); v.y += __shfl_xor(v.y,32,64);
  v.z += __shfl_xor(v.z,32,64); v.w += __shfl_xor(v.w,32,64);
}
__device__ __forceinline__ float dot4(vf4 a, vf4 b){
  return a.x*b.x + a.y*b.y + a.z*b.z + a.w*b.w;
}

// Zero-fill map row i outside its in-graph span [js,je) (NT float4 stores).
__device__ __forceinline__ void fill_row(int i, const int* __restrict__ ub,
    const int* __restrict__ voff, float* __restrict__ mapbase, int Nv, int tid){
  int g = ub[i];
  int js = voff[g], je = voff[g+1];
  float* mrow = mapbase + (size_t)i*Nv;
  const vf4 z4 = {0.f,0.f,0.f,0.f};
  int nf4 = Nv >> 2;
  for (int q4=tid; q4<nf4; q4+=256){
    int j0 = q4*4;
    if (j0+4 <= js || j0 >= je){
      __builtin_nontemporal_store(z4, (vf4*)(mrow + j0));
    } else {
      #pragma unroll
      for(int u=0;u<4;u++){ int j=j0+u; if (j<js || j>=je) mrow[j]=0.f; }
    }
  }
}

// ---- K1: blocks [0,NBn): l2-normalize rows (4 waves/block) + per-row
//  a_i = x_i . h1[0:300], t_i = x_i . h1[300:600] (h1 recomputed from biases
//  in-block -> no cross-block dep);
//  NBn: offsets (binary search) + step-1 LSTM closed form + out init;
//  (NBn, NBn+600]: gbase rows.
__global__ __launch_bounds__(256) void k_norm_off(const float* __restrict__ xu,
    const float* __restrict__ xv, float* __restrict__ su, float* __restrict__ sv,
    int Nu, int Nv, const int* __restrict__ ub, const int* __restrict__ vb,
    int* __restrict__ uoff, int* __restrict__ voff,
    const float* __restrict__ b_ih, const float* __restrict__ b_hh,
    float* __restrict__ h1, float* __restrict__ c1,
    const float* __restrict__ pb, float* __restrict__ outp,
    const float* __restrict__ Wih, const float* __restrict__ Whh,
    float* __restrict__ gbase,
    float* __restrict__ au, float* __restrict__ av,
    float* __restrict__ tu, float* __restrict__ tv){
  int NBn = (Nu + Nv) >> 2;
  int b = blockIdx.x;
  int tid = threadIdx.x, lane = tid & 63, w = tid >> 6;
  __shared__ __align__(16) float h1l[DDIM];
  if (b == NBn){
    int t = tid;
    if (t < NGR){
      int lo=0, hi=Nu;
      while(lo<hi){ int m=(lo+hi)>>1; if (ub[m] < t) lo=m+1; else hi=m; }
      uoff[t]=lo;
      lo=0; hi=Nv;
      while(lo<hi){ int m=(lo+hi)>>1; if (vb[m] < t) lo=m+1; else hi=m; }
      voff[t]=lo;
      if (t==0){ uoff[NGR]=Nu; voff[NGR]=Nv; }
      outp[t] = pb[0];
    }
    for (int d=tid; d<DDIM; d+=256){
      float gi = b_ih[d]      + b_hh[d];
      float gg = b_ih[1200+d] + b_hh[1200+d];
      float go = b_ih[1800+d] + b_hh[1800+d];
      float c  = sigm(gi)*tanhf(gg);       // f*c0 = 0
      c1[d]=c; h1[d]=sigm(go)*tanhf(c);
    }
    return;
  }
  // both remaining branches need bias-only h1 locally
  for (int d=tid; d<DDIM; d+=256){
    float gi = b_ih[d]      + b_hh[d];
    float gg = b_ih[1200+d] + b_hh[1200+d];
    float go = b_ih[1800+d] + b_hh[1800+d];
    float c  = sigm(gi)*tanhf(gg);
    h1l[d]   = sigm(go)*tanhf(c);
  }
  __syncthreads();
  if (b > NBn){                            // gbase blocks
    int n = (b - NBn - 1)*4 + w;           // 600 blocks x 4 waves = 2400 rows
    const float* wi = Wih + (size_t)n*1200;
    const float* wh = Whh + (size_t)n*600;
    float s = 0.f;
    for (int k=lane; k<DDIM; k+=64) s += h1l[k]*(wi[k] + wh[k]);
    s = wred_sum(s);
    if (lane==0) gbase[n] = s + b_ih[n] + b_hh[n];
    return;
  }
  int wid = b*4 + w;
  const float* src; float* dst; float* aout; float* tout; int li;
  if (wid < Nu){ li = wid; src = xu + (size_t)li*HDIM; dst = su + (size_t)li*HDIM;
                 aout = au; tout = tu; }
  else         { li = wid - Nu; src = xv + (size_t)li*HDIM; dst = sv + (size_t)li*HDIM;
                 aout = av; tout = tv; }
  const vf4* s4 = (const vf4*)src;
  vf4 A = s4[lane];
  vf4 Bv = (lane<11)? s4[64+lane] : (vf4){0.f,0.f,0.f,0.f};
  float s = A.x*A.x+A.y*A.y+A.z*A.z+A.w*A.w + Bv.x*Bv.x+Bv.y*Bv.y+Bv.z*Bv.z+Bv.w*Bv.w;
  s = wred_sum(s);
  float inv = 1.f / fmaxf(sqrtf(s), 1e-12f);
  vf4 A2 = A*inv, B2 = Bv*inv;
  vf4* d4 = (vf4*)dst;
  d4[lane] = A2;
  if (lane<11) d4[64+lane] = B2;
  const vf4* q14 = (const vf4*)h1l;            // h1[0:300]
  const vf4* q24 = (const vf4*)(h1l + HDIM);   // h1[300:600] (1200B -> aligned)
  vf4 q1A = q14[lane];
  vf4 q1B = (lane<11)? q14[64+lane] : (vf4){0.f,0.f,0.f,0.f};
  vf4 q2A = q24[lane];
  vf4 q2B = (lane<11)? q24[64+lane] : (vf4){0.f,0.f,0.f,0.f};
  float aa = dot4(A2,q1A) + dot4(B2,q1B);
  float tt = dot4(A2,q2A) + dot4(B2,q2B);
  aa = wred_sum(aa);
  tt = wred_sum(tt);
  if (lane==0){ aout[li] = aa; tout[li] = tt; }
}

// ---- K2 (R9): same scheduling (24576 blocks, b%3==2 -> dedicated fill, 2:1
// interleave); j-loop 2x UNROLLED into two independent chains — wave covers
// 8 partner rows/step (j_a=jb+grp, j_b=jb+4+grp, base js+w*8, stride 32).
// For typical n~32: one step of 2 overlapped {5 loads->dot4->4-shfl} chains
// instead of 2 serial steps; map stores = 32B contiguous pair per wave. ----
__global__ __launch_bounds__(256) void k_prime6(const float* __restrict__ su,
    const float* __restrict__ sv, const int* __restrict__ ub,
    const int* __restrict__ vb, const int* __restrict__ uoff,
    const int* __restrict__ voff, float* __restrict__ spr,
    float* __restrict__ svp, float* __restrict__ e1u, float* __restrict__ e1v,
    const float* __restrict__ au, const float* __restrict__ av,
    const float* __restrict__ tu, const float* __restrict__ tv,
    float* __restrict__ mapbase, int Nu, int Nv){
  int b = blockIdx.x;
  int tid = threadIdx.x, lane = tid & 63, w = tid >> 6;
  int r = b % 3;
  if (r == 2){ fill_row(b/3, ub, voff, mapbase, Nv, tid); return; }
  int idx = (b/3)*2 + r;                   // [0, Nu+Nv)
  bool isU = (idx < Nu);
  int i = isU ? idx : idx - Nu;
  const float* xa = isU ? su : sv;
  const float* xb = isU ? sv : su;
  const int* mybatch = isU ? ub : vb;
  const int* ooff    = isU ? voff : uoff;
  float* prime = isU ? spr : svp;
  float* eout  = isU ? e1u : e1v;
  const float* aarr = isU ? au : av;
  const float* tpar = isU ? tv : tu;       // partner-side t

  __shared__ __align__(16) float prl[4*304];
  __shared__ float red[4];

  int g = mybatch[i];
  int js = ooff[g], je = ooff[g+1];
  int grp = lane >> 4, k16 = lane & 15;
  const vf4 z4 = {0.f,0.f,0.f,0.f};

  const vf4* xr4 = (const vf4*)(xa + (size_t)i*HDIM);
  vf4 x0 = xr4[k16], x1 = xr4[k16+16], x2 = xr4[k16+32], x3 = xr4[k16+48];
  vf4 x4c = (k16<11)? xr4[k16+64] : z4;

  vf4 pr0=z4, pr1=z4, pr2=z4, pr3=z4, pr4=z4;
  float ep = 0.f;
  for (int jb = js + w*8; jb < je; jb += 32){
    int ja = jb + grp;
    int jB = jb + 4 + grp;
    bool acta = (ja < je);
    bool actb = (jB < je);
    int jca = acta ? ja : (je-1);
    int jcb = actb ? jB : (je-1);
    const vf4* ra = (const vf4*)(xb + (size_t)jca*HDIM);
    const vf4* rb = (const vf4*)(xb + (size_t)jcb*HDIM);
    vf4 a0=ra[k16], a1=ra[k16+16], a2=ra[k16+32], a3=ra[k16+48];
    vf4 a4=(k16<11)? ra[k16+64] : z4;
    vf4 b0=rb[k16], b1=rb[k16+16], b2=rb[k16+32], b3=rb[k16+48];
    vf4 b4=(k16<11)? rb[k16+64] : z4;
    float da = dot4(a0,x0)+dot4(a1,x1)+dot4(a2,x2)+dot4(a3,x3)+dot4(a4,x4c);
    float db = dot4(b0,x0)+dot4(b1,x1)+dot4(b2,x2)+dot4(b3,x3)+dot4(b4,x4c);
    da += __shfl_xor(da,1,64);  db += __shfl_xor(db,1,64);
    da += __shfl_xor(da,2,64);  db += __shfl_xor(db,2,64);
    da += __shfl_xor(da,4,64);  db += __shfl_xor(db,4,64);
    da += __shfl_xor(da,8,64);  db += __shfl_xor(db,8,64);
    if (!acta) da = 0.f;
    if (!actb) db = 0.f;
    if (isU && k16==0){
      if (acta) mapbase[(size_t)i*Nv + jca] = da;
      if (actb) mapbase[(size_t)i*Nv + jcb] = db;
    }
    ep += da * tpar[jca] + db * tpar[jcb];   // d=0 masks inactive
    pr0 += da*a0 + db*b0;
    pr1 += da*a1 + db*b1;
    pr2 += da*a2 + db*b2;
    pr3 += da*a3 + db*b3;
    pr4 += da*a4 + db*b4;
  }
  ep = xgrp_sum(ep);
  xgrp_sum4(pr0); xgrp_sum4(pr1); xgrp_sum4(pr2); xgrp_sum4(pr3); xgrp_sum4(pr4);
  if (grp==0){                             // lanes 0..15 write wave partials
    vf4* p4 = (vf4*)(prl + w*304);
    p4[k16] = pr0; p4[k16+16] = pr1; p4[k16+32] = pr2; p4[k16+48] = pr3;
    if (k16<11) p4[k16+64] = pr4;
  }
  if (lane==0) red[w] = ep;
  __syncthreads();
  for (int t=tid; t<HDIM; t+=256){
    float s = prl[t] + prl[304+t] + prl[608+t] + prl[912+t];
    prime[(size_t)i*HDIM + t] = s;
  }
  if (tid==0) eout[i] = aarr[i] + red[0]+red[1]+red[2]+red[3];
}

// ---- K3 (unchanged R8): 1024 blocks, two column-half blocks per (set,g). --
__global__ __launch_bounds__(256) void k_r1(const float* __restrict__ su,
    const float* __restrict__ sv, const float* __restrict__ spr,
    const float* __restrict__ svp, const float* __restrict__ e1u,
    const float* __restrict__ e1v, const int* __restrict__ uoff,
    const int* __restrict__ voff, float* __restrict__ r1){
  int tid = threadIdx.x, lane = tid & 63, w = tid >> 6;
  int bs = blockIdx.x;                     // [0,1024)
  int half = bs & 1; int pair = bs >> 1;   // pair in [0,512)
  int set = pair >> 8; int g = pair & 255;
  const float* x  = set? sv  : su;
  const float* pr = set? svp : spr;
  const float* e  = set? e1v : e1u;
  const int* off  = set? voff: uoff;
  const float* src = half ? pr : x;        // this block's column half
  __shared__ float al[2048]; __shared__ float red[4]; __shared__ float shv;
  int ns = off[g], ne = off[g+1]; int n = ne - ns;
  float m = -INFINITY;
  for (int t=ns+tid; t<ne; t+=256) m = fmaxf(m, e[t]);
  m = wred_max(m);
  if (lane==0) red[w]=m;
  __syncthreads();
  if (tid==0) shv = fmaxf(fmaxf(red[0],red[1]),fmaxf(red[2],red[3]));
  __syncthreads();
  float emax = shv;
  float s = 0.f;
  for (int t=tid; t<n; t+=256){ float a = expf(e[ns+t]-emax); if (t<2048) al[t]=a; s += a; }
  s = wred_sum(s);
  __syncthreads();
  if (lane==0) red[w]=s;
  __syncthreads();
  if (tid==0) shv = red[0]+red[1]+red[2]+red[3];
  __syncthreads();
  float inv = 1.f/(shv + 1e-16f);
  float acc[2] = {0.f,0.f};
  #pragma unroll 4
  for (int nn=0; nn<n; nn++){
    float a = (nn<2048)? al[nn] : expf(e[ns+nn]-emax);
    const float* rr = src + (size_t)(ns+nn)*HDIM;
    #pragma unroll
    for(int u=0;u<2;u++){ int c = tid + u*256; if (c<HDIM) acc[u] += a*rr[c]; }
  }
  #pragma unroll
  for(int u=0;u<2;u++){ int c = tid + u*256; if (c<HDIM)
      r1[(size_t)pair*DDIM + half*HDIM + c] = acc[u]*inv; }
}

// ---- K4: fused GEMM (gates = r1 @ Wih[:,600:].T) + step-2 LSTM pointwise.
// 32 gs x 64 col tile (cols = 4 gates x 16 d), grid 38x16 = 608 blocks. -----
__global__ __launch_bounds__(256) void k_gemm_lstm(const float* __restrict__ r1,
    const float* __restrict__ Wih, const float* __restrict__ gbase,
    const float* __restrict__ c1, float* __restrict__ h2){
  __shared__ __align__(16) float smem[32*68];   // gates phase; K phase aliases
  float* Al = smem;            // 16*36
  float* Bl = smem + 16*36;    // 16*68
  int tid = threadIdx.x;
  int d0  = blockIdx.x*16;     // 38 blocks: d0 = 0..592 (last has 8 valid)
  int gs0 = blockIdx.y*32;
  int tx = tid & 15, ty = tid >> 4;
  float acc[2][4] = {};
  for (int kt=0; kt<600; kt+=16){
    int k = kt + tx;
    bool kok = (k < 600);
    #pragma unroll
    for (int u=0; u<2; u++){
      int rl = ty + u*16;
      Al[tx*36 + rl] = kok ? r1[(size_t)(gs0+rl)*DDIM + k] : 0.f;
    }
    #pragma unroll
    for (int u=0; u<4; u++){
      int cl = ty + u*16;                 // 0..63
      int gate = cl >> 4, dd = cl & 15;
      int d = d0 + dd;
      Bl[tx*68 + cl] = (kok && d < 600)
          ? Wih[(size_t)(gate*600 + d)*1200 + 600 + k] : 0.f;
    }
    __syncthreads();
    #pragma unroll
    for (int kk=0; kk<16; kk++){
      vf2 av = ((const vf2*)(Al + kk*36))[ty];
      vf4 bv = ((const vf4*)(Bl + kk*68))[tx];
      float a[2]={av.x,av.y}, bb[4]={bv.x,bv.y,bv.z,bv.w};
      #pragma unroll
      for(int mm=0;mm<2;mm++)
        #pragma unroll
        for(int nn=0;nn<4;nn++) acc[mm][nn] += a[mm]*bb[nn];
    }
    __syncthreads();
  }
  #pragma unroll
  for (int mm=0; mm<2; mm++){
    vf4 o = {acc[mm][0], acc[mm][1], acc[mm][2], acc[mm][3]};
    ((vf4*)(smem + (ty*2+mm)*68))[tx] = o;
  }
  __syncthreads();
  int d_l = tid & 15, r0 = tid >> 4;
  int d = d0 + d_l;
  if (d < 600){
    float gb_i = gbase[d], gb_f = gbase[600+d], gb_g = gbase[1200+d], gb_o = gbase[1800+d];
    float cc1 = c1[d];
    #pragma unroll
    for (int u=0; u<2; u++){
      int rl = r0 + u*16;
      const float* gr = smem + rl*68;
      float gi = gr[d_l]      + gb_i;
      float gf = gr[16+d_l]   + gb_f;
      float gG = gr[32+d_l]   + gb_g;
      float go = gr[48+d_l]   + gb_o;
      float c  = sigm(gf)*cc1 + sigm(gi)*tanhf(gG);
      h2[(size_t)(gs0+rl)*DDIM + d] = sigm(go)*tanhf(c);
    }
  }
}

// ---- K5 (unchanged R8): 512 blocks; 16-lane-group e2 dot phase. -----------
__global__ __launch_bounds__(256) void k_r2(const float* __restrict__ su,
    const float* __restrict__ sv, const float* __restrict__ spr,
    const float* __restrict__ svp, const int* __restrict__ uoff,
    const int* __restrict__ voff, const float* __restrict__ h2,
    const float* __restrict__ pW, float* __restrict__ e2u,
    float* __restrict__ e2v, float* __restrict__ outp){
  int tid = threadIdx.x, lane = tid & 63, w = tid >> 6;
  int bs = blockIdx.x; int set = bs >> 8; int g = bs & 255;
  const float* x  = set? sv  : su;
  const float* pr = set? svp : spr;
  const int* off  = set? voff: uoff;
  float* e2g      = set? e2v : e2u;        // overflow fallback only
  __shared__ __align__(16) float q[DDIM];
  __shared__ float e2l[128]; __shared__ float al[128];
  __shared__ float red[4]; __shared__ float shv;
  for (int t=tid; t<DDIM; t+=256) q[t] = h2[(size_t)bs*DDIM + t];
  int ns = off[g], ne = off[g+1]; int n = ne - ns;
  __syncthreads();
  int grp = lane >> 4, k16 = lane & 15;
  const vf4 z4 = {0.f,0.f,0.f,0.f};
  const vf4* q4 = (const vf4*)q;           // 150 vf4: [0,75)=x half, [75,150)=prime half
  vf4 qx0=q4[k16], qx1=q4[k16+16], qx2=q4[k16+32], qx3=q4[k16+48];
  vf4 qx4=(k16<11)? q4[k16+64] : z4;
  vf4 qp0=q4[75+k16], qp1=q4[75+k16+16], qp2=q4[75+k16+32], qp3=q4[75+k16+48];
  vf4 qp4=(k16<11)? q4[75+k16+64] : z4;
  for (int nb = ns + w*4; nb < ne; nb += 16){
    int node = nb + grp;
    bool act = (node < ne);
    int nc = act ? node : (ne-1);
    const vf4* xr = (const vf4*)(x  + (size_t)nc*HDIM);
    const vf4* pp = (const vf4*)(pr + (size_t)nc*HDIM);
    vf4 a0=xr[k16], a1=xr[k16+16], a2=xr[k16+32], a3=xr[k16+48];
    vf4 a4=(k16<11)? xr[k16+64] : z4;
    vf4 b0=pp[k16], b1=pp[k16+16], b2=pp[k16+32], b3=pp[k16+48];
    vf4 b4=(k16<11)? pp[k16+64] : z4;
    float d = dot4(a0,qx0)+dot4(a1,qx1)+dot4(a2,qx2)+dot4(a3,qx3)+dot4(a4,qx4)
            + dot4(b0,qp0)+dot4(b1,qp1)+dot4(b2,qp2)+dot4(b3,qp3)+dot4(b4,qp4);
    d += __shfl_xor(d,1,64);
    d += __shfl_xor(d,2,64);
    d += __shfl_xor(d,4,64);
    d += __shfl_xor(d,8,64);
    if (act && k16==0){ int t = nc-ns; if (t<128) e2l[t] = d; else e2g[nc] = d; }
  }
  __syncthreads();
  float m = -INFINITY;
  for (int t=tid; t<n; t+=256) m = fmaxf(m, (t<128)? e2l[t] : e2g[ns+t]);
  m = wred_max(m);
  if (lane==0) red[w]=m;
  __syncthreads();
  if (tid==0) shv = fmaxf(fmaxf(red[0],red[1]),fmaxf(red[2],red[3]));
  __syncthreads();
  float emax = shv;
  float s = 0.f;
  for (int t=tid; t<n; t+=256){
    float a = expf(((t<128)? e2l[t] : e2g[ns+t]) - emax);
    if (t<128) al[t]=a; else e2g[ns+t]=a;
    s += a;
  }
  s = wred_sum(s);
  __syncthreads();
  if (lane==0) red[w]=s;
  __syncthreads();
  if (tid==0) shv = red[0]+red[1]+red[2]+red[3];
  __syncthreads();
  float inv = 1.f/(shv + 1e-16f);
  float acc[3] = {0.f,0.f,0.f};
  #pragma unroll 4
  for (int nn=0; nn<n; nn++){
    float a = (nn<128)? al[nn] : e2g[ns+nn];
    const float* xr = x  + (size_t)(ns+nn)*HDIM;
    const float* pp = pr + (size_t)(ns+nn)*HDIM;
    #pragma unroll
    for(int u=0;u<3;u++){ int c = tid + u*256; if (c<DDIM){
        float xv = (c<HDIM)? xr[c] : pp[c-HDIM]; acc[u] += a*xv; } }
  }
  int hoff = set? 1200 : 0;
  float p = 0.f;
  #pragma unroll
  for(int u=0;u<3;u++){ int c = tid + u*256; if (c<DDIM) p += (acc[u]*inv)*pW[hoff+600+c]; }
  for (int t=tid; t<DDIM; t+=256) p += q[t]*pW[hoff+t];
  p = wred_sum(p);
  __syncthreads();
  if (lane==0) red[w] = p;
  __syncthreads();
  if (tid==0) atomicAdd(&outp[g], red[0]+red[1]+red[2]+red[3]);
}

extern "C" void kernel_launch(void* const* d_in, const int* in_sizes, int n_in,
                              void* d_out, int out_size, void* d_ws, size_t ws_size,
                              hipStream_t stream) {
  const float* solute_x  = (const float*)d_in[0];
  const float* solvent_x = (const float*)d_in[1];
  const int*   ub        = (const int*)d_in[2];
  const int*   vb        = (const int*)d_in[3];
  const float* Wih  = (const float*)d_in[5];
  const float* Whh  = (const float*)d_in[6];
  const float* b_ih = (const float*)d_in[7];
  const float* b_hh = (const float*)d_in[8];
  const float* pW   = (const float*)d_in[9];
  const float* pb   = (const float*)d_in[10];

  int Nu = in_sizes[0] / HDIM;
  int Nv = in_sizes[1] / HDIM;

  float* out = (float*)d_out;
  int predn = out_size - Nu*Nv;        // = 256
  float* mapbase = out + predn;

  float* ws = (float*)d_ws;
  float* su    = ws;
  float* sv    = su    + (size_t)Nu*HDIM;
  float* spr   = sv    + (size_t)Nv*HDIM;
  float* svp   = spr   + (size_t)Nu*HDIM;
  float* e1u   = svp   + (size_t)Nv*HDIM;  // Nu
  float* e1v   = e1u   + Nu;               // Nv
  float* h1    = e1v   + Nv;               // 600
  float* c1    = h1    + DDIM;             // 600
  float* r1    = c1    + DDIM;             // 512*600
  float* gbase = r1    + 512*DDIM;         // 2400
  float* h2    = gbase + 2400;             // 512*600
  float* au    = h2    + 512*DDIM;         // Nu
  float* av    = au    + Nu;               // Nv
  float* tu    = av    + Nv;               // Nu
  float* tv    = tu    + Nu;               // Nv
  int*   uoff  = (int*)(tv + Nv);          // 257
  int*   voff  = uoff + 257;               // 257

  k_norm_off<<<dim3((Nu+Nv)/4 + 1 + 600), dim3(256), 0, stream>>>(
      solute_x, solvent_x, su, sv, Nu, Nv, ub, vb, uoff, voff,
      b_ih, b_hh, h1, c1, pb, out, Wih, Whh, gbase, au, av, tu, tv);
  // 16384 compute blocks + 8192 dedicated fill blocks, 2:1 interleave.
  k_prime6<<<dim3(Nu + Nv + Nu), dim3(256), 0, stream>>>(
      su, sv, ub, vb, uoff, voff, spr, svp, e1u, e1v,
      au, av, tu, tv, mapbase, Nu, Nv);
  k_r1<<<dim3(1024), dim3(256), 0, stream>>>(
      su, sv, spr, svp, e1u, e1v, uoff, voff, r1);
  k_gemm_lstm<<<dim3(38, 16), dim3(256), 0, stream>>>(r1, Wih, gbase, c1, h2);
  k_r2<<<dim3(512), dim3(256), 0, stream>>>(
      su, sv, spr, svp, uoff, voff, h2, pW, e1u, e1v, out);
}

// Round 10
// 493.019 us; speedup vs baseline: 1.0335x; 1.0335x over previous
//
#include <hip/hip_runtime.h>
#include <math.h>

// Problem constants: H=300, D=600, B=256 graphs, Nu=Nv=8192, batch SORTED.
#define HDIM 300
#define DDIM 600
#define NGR  256

typedef float vf4 __attribute__((ext_vector_type(4)));
typedef float vf2 __attribute__((ext_vector_type(2)));

__device__ __forceinline__ float wred_sum(float v){
  #pragma unroll
  for(int o=32;o;o>>=1) v += __shfl_xor(v,o,64);
  return v;
}
__device__ __forceinline__ float wred_max(float v){
  #pragma unroll
  for(int o=32;o;o>>=1) v = fmaxf(v,__shfl_xor(v,o,64));
  return v;
}
__device__ __forceinline__ float sigm(float x){ return 1.f/(1.f+expf(-x)); }

// sum across the 4 16-lane groups (xor bit4 then bit5), all lanes -> total
__device__ __forceinline__ float xgrp_sum(float v){
  v += __shfl_xor(v,16,64);
  v += __shfl_xor(v,32,64);
  return v;
}
__device__ __forceinline__ void xgrp_sum4(vf4& v){
  v.x += __shfl_xor(v.x,16,64); v.y += __shfl_xor(v.y,16,64);
  v.z += __shfl_xor(v.z,16,64); v.w += __shfl_xor(v.w,16,64);
  v.x += __shfl_xor(v.x,32,64); v.y += __shfl_xor(v.y,32,64);
  v.z += __shfl_xor(v.z,32,64); v.w += __shfl_xor(v.w,32,64);
}
__device__ __forceinline__ float dot4(vf4 a, vf4 b){
  return a.x*b.x + a.y*b.y + a.z*b.z + a.w*b.w;
}

// Zero-fill map row i outside its in-graph span [js,je) (NT float4 stores).
__device__ __forceinline__ void fill_row(int i, const int* __restrict__ ub,
    const int* __restrict__ voff, float* __restrict__ mapbase, int Nv, int tid){
  int g = ub[i];
  int js = voff[g], je = voff[g+1];
  float* mrow = mapbase + (size_t)i*Nv;
  const vf4 z4 = {0.f,0.f,0.f,0.f};
  int nf4 = Nv >> 2;
  for (int q4=tid; q4<nf4; q4+=256){
    int j0 = q4*4;
    if (j0+4 <= js || j0 >= je){
      __builtin_nontemporal_store(z4, (vf4*)(mrow + j0));
    } else {
      #pragma unroll
      for(int u=0;u<4;u++){ int j=j0+u; if (j<js || j>=je) mrow[j]=0.f; }
    }
  }
}

// ---- K1: blocks [0,NBn): l2-normalize rows (4 waves/block) + per-row
//  a_i = x_i . h1[0:300], t_i = x_i . h1[300:600] (h1 recomputed from biases
//  in-block -> no cross-block dep);
//  NBn: offsets (binary search) + step-1 LSTM closed form + out init;
//  (NBn, NBn+600]: gbase rows.
__global__ __launch_bounds__(256) void k_norm_off(const float* __restrict__ xu,
    const float* __restrict__ xv, float* __restrict__ su, float* __restrict__ sv,
    int Nu, int Nv, const int* __restrict__ ub, const int* __restrict__ vb,
    int* __restrict__ uoff, int* __restrict__ voff,
    const float* __restrict__ b_ih, const float* __restrict__ b_hh,
    float* __restrict__ h1, float* __restrict__ c1,
    const float* __restrict__ pb, float* __restrict__ outp,
    const float* __restrict__ Wih, const float* __restrict__ Whh,
    float* __restrict__ gbase,
    float* __restrict__ au, float* __restrict__ av,
    float* __restrict__ tu, float* __restrict__ tv){
  int NBn = (Nu + Nv) >> 2;
  int b = blockIdx.x;
  int tid = threadIdx.x, lane = tid & 63, w = tid >> 6;
  __shared__ __align__(16) float h1l[DDIM];
  if (b == NBn){
    int t = tid;
    if (t < NGR){
      int lo=0, hi=Nu;
      while(lo<hi){ int m=(lo+hi)>>1; if (ub[m] < t) lo=m+1; else hi=m; }
      uoff[t]=lo;
      lo=0; hi=Nv;
      while(lo<hi){ int m=(lo+hi)>>1; if (vb[m] < t) lo=m+1; else hi=m; }
      voff[t]=lo;
      if (t==0){ uoff[NGR]=Nu; voff[NGR]=Nv; }
      outp[t] = pb[0];
    }
    for (int d=tid; d<DDIM; d+=256){
      float gi = b_ih[d]      + b_hh[d];
      float gg = b_ih[1200+d] + b_hh[1200+d];
      float go = b_ih[1800+d] + b_hh[1800+d];
      float c  = sigm(gi)*tanhf(gg);       // f*c0 = 0
      c1[d]=c; h1[d]=sigm(go)*tanhf(c);
    }
    return;
  }
  // both remaining branches need bias-only h1 locally
  for (int d=tid; d<DDIM; d+=256){
    float gi = b_ih[d]      + b_hh[d];
    float gg = b_ih[1200+d] + b_hh[1200+d];
    float go = b_ih[1800+d] + b_hh[1800+d];
    float c  = sigm(gi)*tanhf(gg);
    h1l[d]   = sigm(go)*tanhf(c);
  }
  __syncthreads();
  if (b > NBn){                            // gbase blocks
    int n = (b - NBn - 1)*4 + w;           // 600 blocks x 4 waves = 2400 rows
    const float* wi = Wih + (size_t)n*1200;
    const float* wh = Whh + (size_t)n*600;
    float s = 0.f;
    for (int k=lane; k<DDIM; k+=64) s += h1l[k]*(wi[k] + wh[k]);
    s = wred_sum(s);
    if (lane==0) gbase[n] = s + b_ih[n] + b_hh[n];
    return;
  }
  int wid = b*4 + w;
  const float* src; float* dst; float* aout; float* tout; int li;
  if (wid < Nu){ li = wid; src = xu + (size_t)li*HDIM; dst = su + (size_t)li*HDIM;
                 aout = au; tout = tu; }
  else         { li = wid - Nu; src = xv + (size_t)li*HDIM; dst = sv + (size_t)li*HDIM;
                 aout = av; tout = tv; }
  const vf4* s4 = (const vf4*)src;
  vf4 A = s4[lane];
  vf4 Bv = (lane<11)? s4[64+lane] : (vf4){0.f,0.f,0.f,0.f};
  float s = A.x*A.x+A.y*A.y+A.z*A.z+A.w*A.w + Bv.x*Bv.x+Bv.y*Bv.y+Bv.z*Bv.z+Bv.w*Bv.w;
  s = wred_sum(s);
  float inv = 1.f / fmaxf(sqrtf(s), 1e-12f);
  vf4 A2 = A*inv, B2 = Bv*inv;
  vf4* d4 = (vf4*)dst;
  d4[lane] = A2;
  if (lane<11) d4[64+lane] = B2;
  const vf4* q14 = (const vf4*)h1l;            // h1[0:300]
  const vf4* q24 = (const vf4*)(h1l + HDIM);   // h1[300:600] (1200B -> aligned)
  vf4 q1A = q14[lane];
  vf4 q1B = (lane<11)? q14[64+lane] : (vf4){0.f,0.f,0.f,0.f};
  vf4 q2A = q24[lane];
  vf4 q2B = (lane<11)? q24[64+lane] : (vf4){0.f,0.f,0.f,0.f};
  float aa = dot4(A2,q1A) + dot4(B2,q1B);
  float tt = dot4(A2,q2A) + dot4(B2,q2B);
  aa = wred_sum(aa);
  tt = wred_sum(tt);
  if (lane==0){ aout[li] = aa; tout[li] = tt; }
}

// ---- K2 (revert to R8/R7 k_prime5): 24576 blocks, b%3==2 -> dedicated fill,
// 2:1 interleave; 16-lane-group row-parallel j-loop (4 rows/wave/step).
// R9's 2x-unroll variant REGRESSED (+14us: VGPR growth crossed an occupancy
// step; lost TLP > gained ILP) — this geometry is the measured local optimum.
__global__ __launch_bounds__(256) void k_prime5(const float* __restrict__ su,
    const float* __restrict__ sv, const int* __restrict__ ub,
    const int* __restrict__ vb, const int* __restrict__ uoff,
    const int* __restrict__ voff, float* __restrict__ spr,
    float* __restrict__ svp, float* __restrict__ e1u, float* __restrict__ e1v,
    const float* __restrict__ au, const float* __restrict__ av,
    const float* __restrict__ tu, const float* __restrict__ tv,
    float* __restrict__ mapbase, int Nu, int Nv){
  int b = blockIdx.x;
  int tid = threadIdx.x, lane = tid & 63, w = tid >> 6;
  int r = b % 3;
  if (r == 2){ fill_row(b/3, ub, voff, mapbase, Nv, tid); return; }
  int idx = (b/3)*2 + r;                   // [0, Nu+Nv)
  bool isU = (idx < Nu);
  int i = isU ? idx : idx - Nu;
  const float* xa = isU ? su : sv;
  const float* xb = isU ? sv : su;
  const int* mybatch = isU ? ub : vb;
  const int* ooff    = isU ? voff : uoff;
  float* prime = isU ? spr : svp;
  float* eout  = isU ? e1u : e1v;
  const float* aarr = isU ? au : av;
  const float* tpar = isU ? tv : tu;       // partner-side t

  __shared__ __align__(16) float prl[4*304];
  __shared__ float red[4];

  int g = mybatch[i];
  int js = ooff[g], je = ooff[g+1];
  int grp = lane >> 4, k16 = lane & 15;
  const vf4 z4 = {0.f,0.f,0.f,0.f};

  const vf4* xr4 = (const vf4*)(xa + (size_t)i*HDIM);
  vf4 x0 = xr4[k16], x1 = xr4[k16+16], x2 = xr4[k16+32], x3 = xr4[k16+48];
  vf4 x4c = (k16<11)? xr4[k16+64] : z4;

  vf4 pr0=z4, pr1=z4, pr2=z4, pr3=z4, pr4=z4;
  float ep = 0.f;
  for (int jb = js + w*4; jb < je; jb += 16){
    int j = jb + grp;
    bool act = (j < je);
    int jc = act ? j : (je-1);
    const vf4* orow = (const vf4*)(xb + (size_t)jc*HDIM);
    vf4 o0 = orow[k16], o1 = orow[k16+16], o2 = orow[k16+32], o3 = orow[k16+48];
    vf4 o4 = (k16<11)? orow[k16+64] : z4;
    float d = dot4(o0,x0)+dot4(o1,x1)+dot4(o2,x2)+dot4(o3,x3)+dot4(o4,x4c);
    d += __shfl_xor(d,1,64);
    d += __shfl_xor(d,2,64);
    d += __shfl_xor(d,4,64);
    d += __shfl_xor(d,8,64);               // all 16 lanes of group hold dot
    if (!act) d = 0.f;
    if (isU && k16==0 && act) mapbase[(size_t)i*Nv + jc] = d;  // 16B/wave line
    ep += d * tpar[jc];                    // uniform within group (d=0 if !act)
    pr0 += d*o0; pr1 += d*o1; pr2 += d*o2; pr3 += d*o3; pr4 += d*o4;
  }
  ep = xgrp_sum(ep);
  xgrp_sum4(pr0); xgrp_sum4(pr1); xgrp_sum4(pr2); xgrp_sum4(pr3); xgrp_sum4(pr4);
  if (grp==0){                             // lanes 0..15 write wave partials
    vf4* p4 = (vf4*)(prl + w*304);
    p4[k16] = pr0; p4[k16+16] = pr1; p4[k16+32] = pr2; p4[k16+48] = pr3;
    if (k16<11) p4[k16+64] = pr4;
  }
  if (lane==0) red[w] = ep;
  __syncthreads();
  for (int t=tid; t<HDIM; t+=256){
    float s = prl[t] + prl[304+t] + prl[608+t] + prl[912+t];
    prime[(size_t)i*HDIM + t] = s;
  }
  if (tid==0) eout[i] = aarr[i] + red[0]+red[1]+red[2]+red[3];
}

// ---- K3 (R8): 1024 blocks, two column-half blocks per (set,g). ------------
__global__ __launch_bounds__(256) void k_r1(const float* __restrict__ su,
    const float* __restrict__ sv, const float* __restrict__ spr,
    const float* __restrict__ svp, const float* __restrict__ e1u,
    const float* __restrict__ e1v, const int* __restrict__ uoff,
    const int* __restrict__ voff, float* __restrict__ r1){
  int tid = threadIdx.x, lane = tid & 63, w = tid >> 6;
  int bs = blockIdx.x;                     // [0,1024)
  int half = bs & 1; int pair = bs >> 1;   // pair in [0,512)
  int set = pair >> 8; int g = pair & 255;
  const float* x  = set? sv  : su;
  const float* pr = set? svp : spr;
  const float* e  = set? e1v : e1u;
  const int* off  = set? voff: uoff;
  const float* src = half ? pr : x;        // this block's column half
  __shared__ float al[2048]; __shared__ float red[4]; __shared__ float shv;
  int ns = off[g], ne = off[g+1]; int n = ne - ns;
  float m = -INFINITY;
  for (int t=ns+tid; t<ne; t+=256) m = fmaxf(m, e[t]);
  m = wred_max(m);
  if (lane==0) red[w]=m;
  __syncthreads();
  if (tid==0) shv = fmaxf(fmaxf(red[0],red[1]),fmaxf(red[2],red[3]));
  __syncthreads();
  float emax = shv;
  float s = 0.f;
  for (int t=tid; t<n; t+=256){ float a = expf(e[ns+t]-emax); if (t<2048) al[t]=a; s += a; }
  s = wred_sum(s);
  __syncthreads();
  if (lane==0) red[w]=s;
  __syncthreads();
  if (tid==0) shv = red[0]+red[1]+red[2]+red[3];
  __syncthreads();
  float inv = 1.f/(shv + 1e-16f);
  float acc[2] = {0.f,0.f};
  #pragma unroll 4
  for (int nn=0; nn<n; nn++){
    float a = (nn<2048)? al[nn] : expf(e[ns+nn]-emax);
    const float* rr = src + (size_t)(ns+nn)*HDIM;
    #pragma unroll
    for(int u=0;u<2;u++){ int c = tid + u*256; if (c<HDIM) acc[u] += a*rr[c]; }
  }
  #pragma unroll
  for(int u=0;u<2;u++){ int c = tid + u*256; if (c<HDIM)
      r1[(size_t)pair*DDIM + half*HDIM + c] = acc[u]*inv; }
}

// ---- K4: fused GEMM (gates = r1 @ Wih[:,600:].T) + step-2 LSTM pointwise.
// 32 gs x 64 col tile (cols = 4 gates x 16 d), grid 38x16 = 608 blocks. -----
__global__ __launch_bounds__(256) void k_gemm_lstm(const float* __restrict__ r1,
    const float* __restrict__ Wih, const float* __restrict__ gbase,
    const float* __restrict__ c1, float* __restrict__ h2){
  __shared__ __align__(16) float smem[32*68];   // gates phase; K phase aliases
  float* Al = smem;            // 16*36
  float* Bl = smem + 16*36;    // 16*68
  int tid = threadIdx.x;
  int d0  = blockIdx.x*16;     // 38 blocks: d0 = 0..592 (last has 8 valid)
  int gs0 = blockIdx.y*32;
  int tx = tid & 15, ty = tid >> 4;
  float acc[2][4] = {};
  for (int kt=0; kt<600; kt+=16){
    int k = kt + tx;
    bool kok = (k < 600);
    #pragma unroll
    for (int u=0; u<2; u++){
      int rl = ty + u*16;
      Al[tx*36 + rl] = kok ? r1[(size_t)(gs0+rl)*DDIM + k] : 0.f;
    }
    #pragma unroll
    for (int u=0; u<4; u++){
      int cl = ty + u*16;                 // 0..63
      int gate = cl >> 4, dd = cl & 15;
      int d = d0 + dd;
      Bl[tx*68 + cl] = (kok && d < 600)
          ? Wih[(size_t)(gate*600 + d)*1200 + 600 + k] : 0.f;
    }
    __syncthreads();
    #pragma unroll
    for (int kk=0; kk<16; kk++){
      vf2 av = ((const vf2*)(Al + kk*36))[ty];
      vf4 bv = ((const vf4*)(Bl + kk*68))[tx];
      float a[2]={av.x,av.y}, bb[4]={bv.x,bv.y,bv.z,bv.w};
      #pragma unroll
      for(int mm=0;mm<2;mm++)
        #pragma unroll
        for(int nn=0;nn<4;nn++) acc[mm][nn] += a[mm]*bb[nn];
    }
    __syncthreads();
  }
  #pragma unroll
  for (int mm=0; mm<2; mm++){
    vf4 o = {acc[mm][0], acc[mm][1], acc[mm][2], acc[mm][3]};
    ((vf4*)(smem + (ty*2+mm)*68))[tx] = o;
  }
  __syncthreads();
  int d_l = tid & 15, r0 = tid >> 4;
  int d = d0 + d_l;
  if (d < 600){
    float gb_i = gbase[d], gb_f = gbase[600+d], gb_g = gbase[1200+d], gb_o = gbase[1800+d];
    float cc1 = c1[d];
    #pragma unroll
    for (int u=0; u<2; u++){
      int rl = r0 + u*16;
      const float* gr = smem + rl*68;
      float gi = gr[d_l]      + gb_i;
      float gf = gr[16+d_l]   + gb_f;
      float gG = gr[32+d_l]   + gb_g;
      float go = gr[48+d_l]   + gb_o;
      float c  = sigm(gf)*cc1 + sigm(gi)*tanhf(gG);
      h2[(size_t)(gs0+rl)*DDIM + d] = sigm(go)*tanhf(c);
    }
  }
}

// ---- K5 (R8): 512 blocks; 16-lane-group e2 dot phase. ---------------------
__global__ __launch_bounds__(256) void k_r2(const float* __restrict__ su,
    const float* __restrict__ sv, const float* __restrict__ spr,
    const float* __restrict__ svp, const int* __restrict__ uoff,
    const int* __restrict__ voff, const float* __restrict__ h2,
    const float* __restrict__ pW, float* __restrict__ e2u,
    float* __restrict__ e2v, float* __restrict__ outp){
  int tid = threadIdx.x, lane = tid & 63, w = tid >> 6;
  int bs = blockIdx.x; int set = bs >> 8; int g = bs & 255;
  const float* x  = set? sv  : su;
  const float* pr = set? svp : spr;
  const int* off  = set? voff: uoff;
  float* e2g      = set? e2v : e2u;        // overflow fallback only
  __shared__ __align__(16) float q[DDIM];
  __shared__ float e2l[128]; __shared__ float al[128];
  __shared__ float red[4]; __shared__ float shv;
  for (int t=tid; t<DDIM; t+=256) q[t] = h2[(size_t)bs*DDIM + t];
  int ns = off[g], ne = off[g+1]; int n = ne - ns;
  __syncthreads();
  int grp = lane >> 4, k16 = lane & 15;
  const vf4 z4 = {0.f,0.f,0.f,0.f};
  const vf4* q4 = (const vf4*)q;           // 150 vf4: [0,75)=x half, [75,150)=prime half
  vf4 qx0=q4[k16], qx1=q4[k16+16], qx2=q4[k16+32], qx3=q4[k16+48];
  vf4 qx4=(k16<11)? q4[k16+64] : z4;
  vf4 qp0=q4[75+k16], qp1=q4[75+k16+16], qp2=q4[75+k16+32], qp3=q4[75+k16+48];
  vf4 qp4=(k16<11)? q4[75+k16+64] : z4;
  for (int nb = ns + w*4; nb < ne; nb += 16){
    int node = nb + grp;
    bool act = (node < ne);
    int nc = act ? node : (ne-1);
    const vf4* xr = (const vf4*)(x  + (size_t)nc*HDIM);
    const vf4* pp = (const vf4*)(pr + (size_t)nc*HDIM);
    vf4 a0=xr[k16], a1=xr[k16+16], a2=xr[k16+32], a3=xr[k16+48];
    vf4 a4=(k16<11)? xr[k16+64] : z4;
    vf4 b0=pp[k16], b1=pp[k16+16], b2=pp[k16+32], b3=pp[k16+48];
    vf4 b4=(k16<11)? pp[k16+64] : z4;
    float d = dot4(a0,qx0)+dot4(a1,qx1)+dot4(a2,qx2)+dot4(a3,qx3)+dot4(a4,qx4)
            + dot4(b0,qp0)+dot4(b1,qp1)+dot4(b2,qp2)+dot4(b3,qp3)+dot4(b4,qp4);
    d += __shfl_xor(d,1,64);
    d += __shfl_xor(d,2,64);
    d += __shfl_xor(d,4,64);
    d += __shfl_xor(d,8,64);
    if (act && k16==0){ int t = nc-ns; if (t<128) e2l[t] = d; else e2g[nc] = d; }
  }
  __syncthreads();
  float m = -INFINITY;
  for (int t=tid; t<n; t+=256) m = fmaxf(m, (t<128)? e2l[t] : e2g[ns+t]);
  m = wred_max(m);
  if (lane==0) red[w]=m;
  __syncthreads();
  if (tid==0) shv = fmaxf(fmaxf(red[0],red[1]),fmaxf(red[2],red[3]));
  __syncthreads();
  float emax = shv;
  float s = 0.f;
  for (int t=tid; t<n; t+=256){
    float a = expf(((t<128)? e2l[t] : e2g[ns+t]) - emax);
    if (t<128) al[t]=a; else e2g[ns+t]=a;
    s += a;
  }
  s = wred_sum(s);
  __syncthreads();
  if (lane==0) red[w]=s;
  __syncthreads();
  if (tid==0) shv = red[0]+red[1]+red[2]+red[3];
  __syncthreads();
  float inv = 1.f/(shv + 1e-16f);
  float acc[3] = {0.f,0.f,0.f};
  #pragma unroll 4
  for (int nn=0; nn<n; nn++){
    float a = (nn<128)? al[nn] : e2g[ns+nn];
    const float* xr = x  + (size_t)(ns+nn)*HDIM;
    const float* pp = pr + (size_t)(ns+nn)*HDIM;
    #pragma unroll
    for(int u=0;u<3;u++){ int c = tid + u*256; if (c<DDIM){
        float xv = (c<HDIM)? xr[c] : pp[c-HDIM]; acc[u] += a*xv; } }
  }
  int hoff = set? 1200 : 0;
  float p = 0.f;
  #pragma unroll
  for(int u=0;u<3;u++){ int c = tid + u*256; if (c<DDIM) p += (acc[u]*inv)*pW[hoff+600+c]; }
  for (int t=tid; t<DDIM; t+=256) p += q[t]*pW[hoff+t];
  p = wred_sum(p);
  __syncthreads();
  if (lane==0) red[w] = p;
  __syncthreads();
  if (tid==0) atomicAdd(&outp[g], red[0]+red[1]+red[2]+red[3]);
}

extern "C" void kernel_launch(void* const* d_in, const int* in_sizes, int n_in,
                              void* d_out, int out_size, void* d_ws, size_t ws_size,
                              hipStream_t stream) {
  const float* solute_x  = (const float*)d_in[0];
  const float* solvent_x = (const float*)d_in[1];
  const int*   ub        = (const int*)d_in[2];
  const int*   vb        = (const int*)d_in[3];
  const float* Wih  = (const float*)d_in[5];
  const float* Whh  = (const float*)d_in[6];
  const float* b_ih = (const float*)d_in[7];
  const float* b_hh = (const float*)d_in[8];
  const float* pW   = (const float*)d_in[9];
  const float* pb   = (const float*)d_in[10];

  int Nu = in_sizes[0] / HDIM;
  int Nv = in_sizes[1] / HDIM;

  float* out = (float*)d_out;
  int predn = out_size - Nu*Nv;        // = 256
  float* mapbase = out + predn;

  float* ws = (float*)d_ws;
  float* su    = ws;
  float* sv    = su    + (size_t)Nu*HDIM;
  float* spr   = sv    + (size_t)Nv*HDIM;
  float* svp   = spr   + (size_t)Nu*HDIM;
  float* e1u   = svp   + (size_t)Nv*HDIM;  // Nu
  float* e1v   = e1u   + Nu;               // Nv
  float* h1    = e1v   + Nv;               // 600
  float* c1    = h1    + DDIM;             // 600
  float* r1    = c1    + DDIM;             // 512*600
  float* gbase = r1    + 512*DDIM;         // 2400
  float* h2    = gbase + 2400;             // 512*600
  float* au    = h2    + 512*DDIM;         // Nu
  float* av    = au    + Nu;               // Nv
  float* tu    = av    + Nv;               // Nu
  float* tv    = tu    + Nu;               // Nv
  int*   uoff  = (int*)(tv + Nv);          // 257
  int*   voff  = uoff + 257;               // 257

  k_norm_off<<<dim3((Nu+Nv)/4 + 1 + 600), dim3(256), 0, stream>>>(
      solute_x, solvent_x, su, sv, Nu, Nv, ub, vb, uoff, voff,
      b_ih, b_hh, h1, c1, pb, out, Wih, Whh, gbase, au, av, tu, tv);
  // 16384 compute blocks + 8192 dedicated fill blocks, 2:1 interleave.
  k_prime5<<<dim3(Nu + Nv + Nu), dim3(256), 0, stream>>>(
      su, sv, ub, vb, uoff, voff, spr, svp, e1u, e1v,
      au, av, tu, tv, mapbase, Nu, Nv);
  k_r1<<<dim3(1024), dim3(256), 0, stream>>>(
      su, sv, spr, svp, e1u, e1v, uoff, voff, r1);
  k_gemm_lstm<<<dim3(38, 16), dim3(256), 0, stream>>>(r1, Wih, gbase, c1, h2);
  k_r2<<<dim3(512), dim3(256), 0, stream>>>(
      su, sv, spr, svp, uoff, voff, h2, pW, e1u, e1v, out);
}